// Round 10
// baseline (473.808 us; speedup 1.0000x reference)
//
#include <hip/hip_runtime.h>
#include <hip/hip_bf16.h>

#define SLOPE 0.2f
#define EPS_GN 1e-5f
#define APITCH 136  // LDS row pitch in bf16 elems (272 B): 16B-aligned, breaks power-of-2 bank aliasing
#define NBUCK 391   // ceil(100000/256) dst-buckets of 256 nodes

typedef __attribute__((ext_vector_type(8))) short bfrag;   // 8 bf16 = 4 VGPR (MFMA A/B operand)
typedef __attribute__((ext_vector_type(4))) float ffrag;   // 4 fp32 accumulator

__device__ __forceinline__ float lrelu(float v) { return v > 0.f ? v : SLOPE * v; }
__device__ __forceinline__ short f2bs(float v) {
    __hip_bfloat16 h = __float2bfloat16(v);
    return *reinterpret_cast<short*>(&h);
}
__device__ __forceinline__ float blo(unsigned int u) { return __uint_as_float(u << 16); }
__device__ __forceinline__ float bhi(unsigned int u) { return __uint_as_float(u & 0xffff0000u); }

// ====== setup: blocks [0,EB) = bucket histogram; blocks [EB,EB+128) = weights ==
__global__ void __launch_bounds__(256) setup_kernel(
    const int* __restrict__ ei, int* __restrict__ bhist, int E, int N, int EB,
    const float* __restrict__ enc_w, const float* __restrict__ enc_b,
    const float* __restrict__ w1, const float* __restrict__ w2,
    unsigned short* __restrict__ WT1b, unsigned short* __restrict__ WT2b,
    float* __restrict__ bc1, float* __restrict__ bc2) {
    __shared__ int shmem[NBUCK];
    int tid = threadIdx.x;
    if ((int)blockIdx.x < EB) {
        // ---- bucket_hist ----
        for (int i = tid; i < NBUCK; i += 256) shmem[i] = 0;
        __syncthreads();
        int base = blockIdx.x * 4096;
#pragma unroll
        for (int s = 0; s < 16; ++s) {
            int e = base + s * 256 + tid;
            if (e < E + N) {
                int dst = (e < E) ? ei[E + e] : (e - E);
                atomicAdd(&shmem[dst >> 8], 1);
            }
        }
        __syncthreads();
        for (int i = tid; i < NBUCK; i += 256)
            if (shmem[i]) atomicAdd(&bhist[i], shmem[i]);
    } else {
        // ---- prep_weights: WT1b[c][k] = bf16((w1@enc_w)[c,k]); bc1 = w1@enc_b
        int c = blockIdx.x - EB;   // 0..127 (output channel)
        float* w1row = (float*)shmem;
        if (tid < 128) w1row[tid] = w1[c * 128 + tid];
        __syncthreads();
        if (tid < 128) {
            int k = tid;
            float acc = 0.f;
            for (int j = 0; j < 128; ++j)
                acc = fmaf(w1row[j], enc_w[j * 128 + k], acc);
            WT1b[c * 128 + k] = (unsigned short)f2bs(acc);
            WT2b[c * 128 + k] = (unsigned short)f2bs(w2[c * 128 + k]);
            if (k == 0) {
                float b = 0.f;
                for (int j = 0; j < 128; ++j) b += w1row[j] * enc_b[j];
                bc1[c] = b;
                bc2[c] = 0.f;
            }
        }
    }
}

// ============ CSR build: two-level bucketed counting sort =====================
// bucket b = dst >> 8 (256 nodes/bucket). Staged word = (src<<8)|(dst&255).

__global__ void bucket_scan(const int* __restrict__ bhist,
                            int* __restrict__ bbase, int* __restrict__ bcur) {
    __shared__ int sh[512];
    int t = threadIdx.x;  // 512 threads
    int v = (t < NBUCK) ? bhist[t] : 0;
    sh[t] = v;
    __syncthreads();
    for (int off = 1; off < 512; off <<= 1) {
        int add = (t >= off) ? sh[t - off] : 0;
        __syncthreads();
        sh[t] += add;
        __syncthreads();
    }
    if (t < NBUCK) {
        bbase[t] = sh[t] - v;
        bcur[t] = sh[t] - v;
    }
}

__global__ void __launch_bounds__(256) bucket_scatter(const int* __restrict__ ei,
                                                      int* __restrict__ bcur,
                                                      unsigned int* __restrict__ staging,
                                                      int E, int N) {
    __shared__ int h[NBUCK];
    __shared__ int lb[NBUCK];
    for (int i = threadIdx.x; i < NBUCK; i += 256) h[i] = 0;
    __syncthreads();
    int base = blockIdx.x * 4096;
    int srcv[16], dstv[16];
#pragma unroll
    for (int s = 0; s < 16; ++s) {
        int e = base + s * 256 + threadIdx.x;
        srcv[s] = -1;
        if (e < E + N) {
            srcv[s] = (e < E) ? ei[e] : (e - E);
            dstv[s] = (e < E) ? ei[E + e] : (e - E);
            atomicAdd(&h[dstv[s] >> 8], 1);
        }
    }
    __syncthreads();
    for (int i = threadIdx.x; i < NBUCK; i += 256) {
        int c = h[i];
        lb[i] = c ? atomicAdd(&bcur[i], c) : 0;
        h[i] = 0;  // reuse as within-block cursor
    }
    __syncthreads();
#pragma unroll
    for (int s = 0; s < 16; ++s) {
        if (srcv[s] >= 0) {
            int b = dstv[s] >> 8;
            int slot = atomicAdd(&h[b], 1);
            staging[lb[b] + slot] = ((unsigned int)srcv[s] << 8) | (unsigned int)(dstv[s] & 255);
        }
    }
}

// fused: per-bucket degree hist -> LDS exclusive scan -> rowp -> CSR scatter.
__global__ void __launch_bounds__(256) bucket_finalize(
    const unsigned int* __restrict__ staging,
    const int* __restrict__ bbase, const int* __restrict__ bcur,
    int* __restrict__ rowp, int* __restrict__ esrc, int N, int Etot) {
    int b = blockIdx.x, t = threadIdx.x;
    __shared__ int h[256], sc[256];
    h[t] = 0;
    __syncthreads();
    int s0 = bbase[b], s1 = bcur[b];
    for (int j = s0 + t; j < s1; j += 256)
        atomicAdd(&h[staging[j] & 255], 1);
    __syncthreads();
    int d = h[t];
    sc[t] = d;
    __syncthreads();
    for (int off = 1; off < 256; off <<= 1) {
        int add = (t >= off) ? sc[t - off] : 0;
        __syncthreads();
        sc[t] += add;
        __syncthreads();
    }
    int excl = s0 + sc[t] - d;
    int node = b * 256 + t;
    if (node < N) rowp[node] = excl;
    if (b == 0 && t == 0) rowp[N] = Etot;
    __syncthreads();
    h[t] = excl;  // within-bucket cursors
    __syncthreads();
    for (int j = s0 + t; j < s1; j += 256) {
        unsigned int p = staging[j];
        int pos = atomicAdd(&h[p & 255], 1);
        esrc[pos] = (int)(p >> 8);
    }
}

// --------- MFMA GEMM: H[n][128] (bf16) = act(A[n][128]) @ WT^T + bc; + scores --
// Direct global->register fragment loads (no input LDS staging):
//   B frag = 16 contiguous bytes of c-major WTb (L1/L2-resident, 64 KB total).
//   A frag = lane's own row slice (fp32->bf16 cvt layer 1; bf16+norm layer 2).
// LDS holds only the C epilogue buffer -> ~19 KB -> ~5 blocks/CU (was 2).
__global__ void __launch_bounds__(256) gemm_mfma(
    const void* __restrict__ Ain, const unsigned short* __restrict__ WTb,
    const float* __restrict__ bias, const float* __restrict__ att_src,
    const float* __restrict__ att_dst, const int* __restrict__ batch,
    const float* __restrict__ Ac, const float* __restrict__ Bc,
    unsigned int* __restrict__ H, float* __restrict__ ssrc, float* __restrict__ sdst, int N) {
    __shared__ short Csh[64 * APITCH];  // C epilogue only
    __shared__ float asrc_s[128], adst_s[128], bias_s[128];
    int tid = threadIdx.x;
    int base = blockIdx.x * 64;
    if (tid < 128) {
        asrc_s[tid] = att_src[tid];
        adst_s[tid] = att_dst[tid];
        bias_s[tid] = bias[tid];
    }

    int w = tid >> 6, lane = tid & 63, col = lane & 15, quad = lane >> 4;
    int rowBase = w * 16;
    int node = base + rowBase + col;
    bool valid = node < N;

    // A fragments: A[m=col][k=quad*8+j] (HW-verified m89/m91/m118 layout)
    bfrag afr[4];
    if (Ac == nullptr) {
        const float* A = (const float*)Ain;
#pragma unroll
        for (int s = 0; s < 4; ++s) {
            short o[8] = {0, 0, 0, 0, 0, 0, 0, 0};
            if (valid) {
                int k8 = s * 32 + quad * 8;
                float4 v0 = *(const float4*)&A[(size_t)node * 128 + k8];
                float4 v1 = *(const float4*)&A[(size_t)node * 128 + k8 + 4];
                o[0] = f2bs(v0.x); o[1] = f2bs(v0.y); o[2] = f2bs(v0.z); o[3] = f2bs(v0.w);
                o[4] = f2bs(v1.x); o[5] = f2bs(v1.y); o[6] = f2bs(v1.z); o[7] = f2bs(v1.w);
            }
            afr[s] = *(bfrag*)o;
        }
    } else {
        const uint4* A4 = (const uint4*)Ain;
        int g = valid ? batch[node] : 0;
#pragma unroll
        for (int s = 0; s < 4; ++s) {
            short o[8] = {0, 0, 0, 0, 0, 0, 0, 0};
            if (valid) {
                int k8 = s * 32 + quad * 8;
                uint4 hb = A4[(size_t)node * 16 + s * 4 + quad];
                float4 a0 = *(const float4*)&Ac[g * 128 + k8];
                float4 a1 = *(const float4*)&Ac[g * 128 + k8 + 4];
                float4 b0 = *(const float4*)&Bc[g * 128 + k8];
                float4 b1 = *(const float4*)&Bc[g * 128 + k8 + 4];
                o[0] = f2bs(fmaf(blo(hb.x), a0.x, b0.x));
                o[1] = f2bs(fmaf(bhi(hb.x), a0.y, b0.y));
                o[2] = f2bs(fmaf(blo(hb.y), a0.z, b0.z));
                o[3] = f2bs(fmaf(bhi(hb.y), a0.w, b0.w));
                o[4] = f2bs(fmaf(blo(hb.z), a1.x, b1.x));
                o[5] = f2bs(fmaf(bhi(hb.z), a1.y, b1.y));
                o[6] = f2bs(fmaf(blo(hb.w), a1.z, b1.z));
                o[7] = f2bs(fmaf(bhi(hb.w), a1.w, b1.w));
            }
            afr[s] = *(bfrag*)o;
        }
    }

    ffrag acc[8];
#pragma unroll
    for (int t = 0; t < 8; ++t) acc[t] = (ffrag){0.f, 0.f, 0.f, 0.f};

#pragma unroll
    for (int t = 0; t < 8; ++t) {
#pragma unroll
        for (int s = 0; s < 4; ++s) {
            bfrag bfr = *(const bfrag*)&WTb[(t * 16 + col) * 128 + s * 32 + quad * 8];
            acc[t] = __builtin_amdgcn_mfma_f32_16x16x32_bf16(afr[s], bfr, acc[t], 0, 0, 0);
        }
    }

    __syncthreads();  // asrc/adst/bias staged; Csh free
    // C (+ folded bias) into Csh rows (C layout: col=lane&15, row=quad*4+reg)
#pragma unroll
    for (int t = 0; t < 8; ++t) {
        int ch = t * 16 + col;
        float bv = bias_s[ch];
#pragma unroll
        for (int r = 0; r < 4; ++r)
            Csh[(rowBase + quad * 4 + r) * APITCH + ch] = f2bs(acc[t][r] + bv);
    }
    __syncthreads();

    // coalesced copy-out + attention scores (width-16 shuffle reduce per head)
    float2 av = make_float2(asrc_s[lane * 2], asrc_s[lane * 2 + 1]);
    float2 dv = make_float2(adst_s[lane * 2], adst_s[lane * 2 + 1]);
    for (int r = 0; r < 16; ++r) {
        int n2 = base + rowBase + r;
        unsigned int hb = *(const unsigned int*)&Csh[(rowBase + r) * APITCH + lane * 2];
        float hx = blo(hb);
        float hy = bhi(hb);
        float vs = hx * av.x + hy * av.y;
        float vd = hx * dv.x + hy * dv.y;
#pragma unroll
        for (int off = 8; off; off >>= 1) {
            vs += __shfl_xor(vs, off, 16);
            vd += __shfl_xor(vd, off, 16);
        }
        if (n2 < N) {
            H[n2 * 64 + lane] = hb;
            if ((lane & 15) == 0) {
                int h = lane >> 4;
                ssrc[n2 * 4 + h] = vs;
                sdst[n2 * 4 + h] = vd;
            }
        }
    }
}

// ------- aggregation: single-pass softmax num+den; ONE WAVE PER NODE ----------
// (round-5 form: max MLP across 100k waves; fusion attempts regress — R7)
__global__ void __launch_bounds__(256) agg_kernel(
    const int* __restrict__ row, const int* __restrict__ esrc,
    const float* __restrict__ ssrc, const float* __restrict__ sdst,
    const uint4* __restrict__ H4, const float* __restrict__ bias,
    uint4* __restrict__ out, int N) {
    int n = (blockIdx.x * 256 + threadIdx.x) >> 6;
    int lane = threadIdx.x & 63;
    if (n >= N) return;
    int slot = lane >> 4, li = lane & 15, head = li >> 2;
    int beg = row[n], end = row[n + 1];
    float sdh = sdst[n * 4 + head];

    float num[8] = {0.f, 0.f, 0.f, 0.f, 0.f, 0.f, 0.f, 0.f};
    float den = 0.f;
    for (int e = beg + slot; e < end; e += 4) {
        int s = esrc[e];
        float al = __expf(lrelu(ssrc[s * 4 + head] + sdh));
        uint4 hb = H4[s * 16 + li];
        den += al;
        num[0] = fmaf(al, blo(hb.x), num[0]);
        num[1] = fmaf(al, bhi(hb.x), num[1]);
        num[2] = fmaf(al, blo(hb.y), num[2]);
        num[3] = fmaf(al, bhi(hb.y), num[3]);
        num[4] = fmaf(al, blo(hb.z), num[4]);
        num[5] = fmaf(al, bhi(hb.z), num[5]);
        num[6] = fmaf(al, blo(hb.w), num[6]);
        num[7] = fmaf(al, bhi(hb.w), num[7]);
    }
    den += __shfl_xor(den, 16);
    den += __shfl_xor(den, 32);
#pragma unroll
    for (int j = 0; j < 8; ++j) {
        num[j] += __shfl_xor(num[j], 16);
        num[j] += __shfl_xor(num[j], 32);
    }
    if (slot == 0) {
        float rh = 1.f / den;
        int c0 = li * 8;
        unsigned int o[4];
#pragma unroll
        for (int p = 0; p < 4; ++p) {
            float v0 = fmaf(num[2 * p], rh, bias[c0 + 2 * p]);
            float v1 = fmaf(num[2 * p + 1], rh, bias[c0 + 2 * p + 1]);
            v0 = v0 > 0.f ? v0 : __expf(v0) - 1.f;  // ELU
            v1 = v1 > 0.f ? v1 : __expf(v1) - 1.f;
            o[p] = ((unsigned int)(unsigned short)f2bs(v0)) |
                   (((unsigned int)(unsigned short)f2bs(v1)) << 16);
        }
        out[n * 16 + li] = make_uint4(o[0], o[1], o[2], o[3]);
    }
}

// ------- GraphNorm stats (+ max/min for layer 2) — ATOMIC-FREE ----------------
// Stage 1: per-block partials via plain coalesced stores. part[b][q][128],
// q: 0=sum(set0) 1=sq(set0) 2=sum(set1) 3=sq(set1) 4=mx0 5=mn0 6=mx1 7=mn1.
template <int POOL>
__global__ void __launch_bounds__(256) stats_kernel(
    const uint4* __restrict__ X4, const int* __restrict__ batch,
    float* __restrict__ part, int N) {
    __shared__ float red[16][16][9];  // [rowgroup][u4][ch(+pad)]
    int t = threadIdx.x, u4 = t & 15, rg = t >> 4;
    int base = blockIdx.x * 64;
    int g0 = batch[base];

    float s[2][8] = {}, q[2][8] = {};
    float mx[2][8], mn[2][8];
#pragma unroll
    for (int st = 0; st < 2; ++st)
#pragma unroll
        for (int p = 0; p < 8; ++p) { mx[st][p] = -3e38f; mn[st][p] = 3e38f; }

#pragma unroll
    for (int rr = 0; rr < 4; ++rr) {
        int node = base + rg + rr * 16;
        if (node < N) {
            uint4 hb = X4[node * 16 + u4];
            int st = (batch[node] != g0) ? 1 : 0;
            float vv[8] = {blo(hb.x), bhi(hb.x), blo(hb.y), bhi(hb.y),
                           blo(hb.z), bhi(hb.z), blo(hb.w), bhi(hb.w)};
#pragma unroll
            for (int p = 0; p < 8; ++p) {
                s[st][p] += vv[p];
                q[st][p] += vv[p] * vv[p];
                if (POOL) {
                    mx[st][p] = fmaxf(mx[st][p], vv[p]);
                    mn[st][p] = fminf(mn[st][p], vv[p]);
                }
            }
        }
    }

    int uu = t >> 3, ch = t & 7;  // reducer mapping (threads 0..127 -> channel t)
    float rs[2] = {0.f, 0.f}, rq[2] = {0.f, 0.f};
    float rmx[2] = {-3e38f, -3e38f}, rmn[2] = {3e38f, 3e38f};
    for (int st = 0; st < 2; ++st) {
#pragma unroll
        for (int p = 0; p < 8; ++p) red[rg][u4][p] = s[st][p];
        __syncthreads();
        if (t < 128) { float a = 0.f; for (int r2 = 0; r2 < 16; ++r2) a += red[r2][uu][ch]; rs[st] = a; }
        __syncthreads();
#pragma unroll
        for (int p = 0; p < 8; ++p) red[rg][u4][p] = q[st][p];
        __syncthreads();
        if (t < 128) { float a = 0.f; for (int r2 = 0; r2 < 16; ++r2) a += red[r2][uu][ch]; rq[st] = a; }
        __syncthreads();
        if (POOL) {
#pragma unroll
            for (int p = 0; p < 8; ++p) red[rg][u4][p] = mx[st][p];
            __syncthreads();
            if (t < 128) { float a = -3e38f; for (int r2 = 0; r2 < 16; ++r2) a = fmaxf(a, red[r2][uu][ch]); rmx[st] = a; }
            __syncthreads();
#pragma unroll
            for (int p = 0; p < 8; ++p) red[rg][u4][p] = mn[st][p];
            __syncthreads();
            if (t < 128) { float a = 3e38f; for (int r2 = 0; r2 < 16; ++r2) a = fminf(a, red[r2][uu][ch]); rmn[st] = a; }
            __syncthreads();
        }
    }
    if (t < 128) {
        float* pb = part + (size_t)blockIdx.x * 8 * 128;
        pb[0 * 128 + t] = rs[0];
        pb[1 * 128 + t] = rq[0];
        pb[2 * 128 + t] = rs[1];
        pb[3 * 128 + t] = rq[1];
        if (POOL) {
            pb[4 * 128 + t] = rmx[0];
            pb[5 * 128 + t] = rmn[0];
            pb[6 * 128 + t] = rmx[1];
            pb[7 * 128 + t] = rmn[1];
        }
    }
}

// Stage 2 (layer 1): per-group gather of block partials -> Ac/Bc coefficients.
__global__ void reduce_coef(const float* __restrict__ part,
                            const int* __restrict__ batch, int N,
                            const float* __restrict__ w, const float* __restrict__ b,
                            const float* __restrict__ ms,
                            float* __restrict__ Ac, float* __restrict__ Bc) {
    __shared__ int sh2[2];
    int g = blockIdx.x, c = threadIdx.x;  // 64 x 128
    if (c < 2) {
        int key = g + c;
        int lo = 0, hi = N;
        while (lo < hi) { int m = (lo + hi) >> 1; if (batch[m] < key) lo = m + 1; else hi = m; }
        sh2[c] = lo;
    }
    __syncthreads();
    int sidx = sh2[0], eidx = sh2[1];
    float cnt = (float)(eidx - sidx);
    if (cnt < 0.5f) { Ac[g * 128 + c] = 0.f; Bc[g * 128 + c] = 0.f; return; }
    int b0 = sidx >> 6, b1 = (eidx - 1) >> 6;
    float s = 0.f, q = 0.f;
    for (int bb = b0; bb <= b1; ++bb) {
        int g0b = batch[bb << 6];
        int qoff;
        bool take;
        if (g0b == g) { qoff = 0; take = true; }
        else {
            int g1b = batch[min((bb << 6) + 63, N - 1)];
            take = (g1b == g);
            qoff = 2;
        }
        if (take) {
            const float* pb = part + (size_t)bb * 8 * 128;
            s += pb[qoff * 128 + c];
            q += pb[(qoff + 1) * 128 + c];
        }
    }
    float mean = s / cnt;
    float msv = ms[c];
    float var = q / cnt - msv * (2.f - msv) * mean * mean;
    var = fmaxf(var, 0.f);
    float inv = rsqrtf(var + EPS_GN);
    float a = w[c] * inv;
    Ac[g * 128 + c] = a;
    Bc[g * 128 + c] = b[c] - msv * mean * a;
}

// Stage 2 (layer 2) fused with FC: block g computes pooled[g][:] (monotone
// affine of raw max/min), then out[g][:] = pooled . fcw^T + fcb.
__global__ void __launch_bounds__(128) reduce_fc(
    const float* __restrict__ part, const int* __restrict__ batch, int N,
    const float* __restrict__ w, const float* __restrict__ b,
    const float* __restrict__ ms,
    const float* __restrict__ fcw, const float* __restrict__ fcb,
    float* __restrict__ out) {
    __shared__ int sh2[2];
    __shared__ float p[128];
    int g = blockIdx.x, c = threadIdx.x;  // 64 x 128
    if (c < 2) {
        int key = g + c;
        int lo = 0, hi = N;
        while (lo < hi) { int m = (lo + hi) >> 1; if (batch[m] < key) lo = m + 1; else hi = m; }
        sh2[c] = lo;
    }
    __syncthreads();
    int sidx = sh2[0], eidx = sh2[1];
    float cnt = (float)(eidx - sidx);
    if (cnt < 0.5f) {
        p[c] = 0.f;
    } else {
        int b0 = sidx >> 6, b1 = (eidx - 1) >> 6;
        float s = 0.f, q = 0.f, M = -3e38f, m = 3e38f;
        for (int bb = b0; bb <= b1; ++bb) {
            int g0b = batch[bb << 6];
            int qoff;
            bool take;
            if (g0b == g) { qoff = 0; take = true; }
            else {
                int g1b = batch[min((bb << 6) + 63, N - 1)];
                take = (g1b == g);
                qoff = 2;
            }
            if (take) {
                const float* pb = part + (size_t)bb * 8 * 128;
                s += pb[qoff * 128 + c];
                q += pb[(qoff + 1) * 128 + c];
                M = fmaxf(M, pb[(4 + qoff) * 128 + c]);
                m = fminf(m, pb[(5 + qoff) * 128 + c]);
            }
        }
        float mean = s / cnt;
        float msv = ms[c];
        float var = q / cnt - msv * (2.f - msv) * mean * mean;
        var = fmaxf(var, 0.f);
        float inv = rsqrtf(var + EPS_GN);
        float a = w[c] * inv;
        float bb2 = b[c] - msv * mean * a;
        p[c] = (a >= 0.f) ? fmaf(a, M, bb2) : fmaf(a, m, bb2);
    }
    __syncthreads();
    if (c < 64) {
        float acc = fcb[c];
        for (int k = 0; k < 128; ++k)
            acc = fmaf(p[k], fcw[c * 128 + k], acc);
        out[g * 64 + c] = acc;
    }
}

extern "C" void kernel_launch(void* const* d_in, const int* in_sizes, int n_in,
                              void* d_out, int out_size, void* d_ws, size_t ws_size,
                              hipStream_t stream) {
    const float* x     = (const float*)d_in[0];
    const int* ei      = (const int*)d_in[1];
    const int* batch   = (const int*)d_in[2];
    const float* enc_w = (const float*)d_in[3];
    const float* enc_b = (const float*)d_in[4];
    const float* w1    = (const float*)d_in[5];
    const float* as1   = (const float*)d_in[6];
    const float* ad1   = (const float*)d_in[7];
    const float* b1    = (const float*)d_in[8];
    const float* n1w   = (const float*)d_in[9];
    const float* n1b   = (const float*)d_in[10];
    const float* n1ms  = (const float*)d_in[11];
    const float* w2    = (const float*)d_in[12];
    const float* as2   = (const float*)d_in[13];
    const float* ad2   = (const float*)d_in[14];
    const float* b2    = (const float*)d_in[15];
    const float* n2w   = (const float*)d_in[16];
    const float* n2b   = (const float*)d_in[17];
    const float* n2ms  = (const float*)d_in[18];
    const float* fcw   = (const float*)d_in[19];
    const float* fcb   = (const float*)d_in[20];
    float* out = (float*)d_out;

    int N = in_sizes[2];
    int E = in_sizes[1] / 2;
    int Etot = E + N;
    int SB = (N + 63) / 64;
    int EB = (Etot + 4095) / 4096;

    char* ws = (char*)d_ws;
    size_t off = 0;
    auto take = [&](size_t bytes) {
        char* p = ws + off;
        off = (off + bytes + 255) & ~(size_t)255;
        return p;
    };
    unsigned short* WT1b = (unsigned short*)take(128 * 128 * 2);
    unsigned short* WT2b = (unsigned short*)take(128 * 128 * 2);
    float* bc1 = (float*)take(512);
    float* bc2 = (float*)take(512);
    float* ssrc = (float*)take((size_t)N * 16);
    float* sdst = (float*)take((size_t)N * 16);
    int* rowp   = (int*)take((size_t)(N + 1) * 4);
    int* esrc   = (int*)take((size_t)Etot * 4);
    unsigned int* staging = (unsigned int*)take((size_t)Etot * 4);
    int* bbase  = (int*)take(512 * 4);
    int* bcur   = (int*)take(512 * 4);
    int* bhist  = (int*)take(512 * 4);
    unsigned int* H = (unsigned int*)take((size_t)N * 256);  // bf16 [N][128]
    unsigned int* AG = (unsigned int*)take((size_t)N * 256); // bf16 [N][128]
    float* Ac   = (float*)take(64 * 128 * 4);
    float* Bc   = (float*)take(64 * 128 * 4);
    float* part = (float*)take((size_t)SB * 8 * 128 * 4);    // per-block partials
    if (off > ws_size) return;  // workspace too small -> output stays zero

    hipMemsetAsync(bhist, 0, 512 * 4, stream);
    // fused: bucket histogram (blocks 0..EB-1) + weight prep (blocks EB..EB+127)
    setup_kernel<<<EB + 128, 256, 0, stream>>>(ei, bhist, E, N, EB,
                                               enc_w, enc_b, w1, w2,
                                               WT1b, WT2b, bc1, bc2);
    bucket_scan<<<1, 512, 0, stream>>>(bhist, bbase, bcur);
    bucket_scatter<<<EB, 256, 0, stream>>>(ei, bcur, staging, E, N);
    bucket_finalize<<<NBUCK, 256, 0, stream>>>(staging, bbase, bcur, rowp, esrc, N, Etot);

    // ---- layer 1 (encoder folded into WT1b/bc1) ----
    gemm_mfma<<<(N + 63) / 64, 256, 0, stream>>>(x, WT1b, bc1, as1, ad1, batch,
                                                 nullptr, nullptr, H, ssrc, sdst, N);
    agg_kernel<<<(N + 3) / 4, 256, 0, stream>>>(rowp, esrc, ssrc, sdst,
                                                (const uint4*)H, b1, (uint4*)AG, N);
    stats_kernel<0><<<SB, 256, 0, stream>>>((const uint4*)AG, batch, part, N);
    reduce_coef<<<64, 128, 0, stream>>>(part, batch, N, n1w, n1b, n1ms, Ac, Bc);

    // ---- layer 2 (GraphNorm fused into gemm A-load; stats+pool one pass) ----
    gemm_mfma<<<(N + 63) / 64, 256, 0, stream>>>(AG, WT2b, bc2, as2, ad2, batch,
                                                 Ac, Bc, H, ssrc, sdst, N);
    agg_kernel<<<(N + 3) / 4, 256, 0, stream>>>(rowp, esrc, ssrc, sdst,
                                                (const uint4*)H, b2, (uint4*)AG, N);
    stats_kernel<1><<<SB, 256, 0, stream>>>((const uint4*)AG, batch, part, N);
    reduce_fc<<<64, 128, 0, stream>>>(part, batch, N, n2w, n2b, n2ms, fcw, fcb, out);
}